// Round 1
// baseline (246.688 us; speedup 1.0000x reference)
//
#include <hip/hip_runtime.h>
#include <hip/hip_bf16.h>
#include <stdint.h>

typedef __attribute__((ext_vector_type(8))) __bf16 bf16x8;
typedef __attribute__((ext_vector_type(4))) float  f32x4;

__device__ __forceinline__ ushort f2bf(float f) {
    union { float f; uint32_t u; } v; v.f = f;
    uint32_t u = v.u;
    uint32_t r = 0x7FFFu + ((u >> 16) & 1u);
    return (ushort)((u + r) >> 16);
}

// ---------------- convert fp32 -> bf16 (vectorized) ----------------
__global__ __launch_bounds__(256) void convert_bf16(const float* __restrict__ src,
                                                    ushort* __restrict__ dst, int n4) {
    int i = blockIdx.x * 256 + threadIdx.x;
    if (i < n4) {
        float4 f = ((const float4*)src)[i];
        ushort4 o;
        o.x = f2bf(f.x); o.y = f2bf(f.y); o.z = f2bf(f.z); o.w = f2bf(f.w);
        ((ushort4*)dst)[i] = o;
    }
}

// ---------------- QKV projection GEMM: Y = X @ W^T + b ----------------
// X: [4096,1024] bf16, W: [1024,1024] bf16 (row-major [N,K]).
// z=0 -> k ([B,H,S,DH]), z=1 -> q ([B,H,S,DH]), z=2 -> v transposed ([B,H,DH,S]).
__global__ __launch_bounds__(256) void proj_gemm(
    const ushort* __restrict__ xb, const ushort* __restrict__ wball,
    const float* __restrict__ bk, const float* __restrict__ bq, const float* __restrict__ bv,
    ushort* __restrict__ kd, ushort* __restrict__ qd, ushort* __restrict__ vd)
{
    __shared__ ushort As[128 * 32];
    __shared__ ushort Bs[128 * 32];
    const int z = blockIdx.z;
    const int row0 = blockIdx.x * 128;
    const int col0 = blockIdx.y * 128;
    const ushort* wb = wball + z * 1048576;
    const int tid = threadIdx.x;
    const int lane = tid & 63, wave = tid >> 6;
    const int quad = lane >> 4, m15 = lane & 15;
    const int wr = wave >> 1, wc = wave & 1;

    f32x4 acc[4][4];
    for (int i = 0; i < 4; i++)
        for (int j = 0; j < 4; j++) acc[i][j] = (f32x4){0.f, 0.f, 0.f, 0.f};

    for (int kk = 0; kk < 1024; kk += 32) {
        __syncthreads();
        for (int i = 0; i < 2; i++) {
            int c = tid + i * 256;          // 512 chunks of 16B per tile
            int r = c >> 2, off = (c & 3) * 8;
            *(uint4*)&As[r * 32 + off] = *(const uint4*)&xb[(row0 + r) * 1024 + kk + off];
            *(uint4*)&Bs[r * 32 + off] = *(const uint4*)&wb[(col0 + r) * 1024 + kk + off];
        }
        __syncthreads();
        bf16x8 af[4], bfv[4];
        for (int fr = 0; fr < 4; fr++)
            af[fr] = *(const bf16x8*)&As[(wr * 64 + fr * 16 + m15) * 32 + quad * 8];
        for (int fc = 0; fc < 4; fc++)
            bfv[fc] = *(const bf16x8*)&Bs[(wc * 64 + fc * 16 + m15) * 32 + quad * 8];
        for (int fr = 0; fr < 4; fr++)
            for (int fc = 0; fc < 4; fc++)
                acc[fr][fc] = __builtin_amdgcn_mfma_f32_16x16x32_bf16(af[fr], bfv[fc], acc[fr][fc], 0, 0, 0);
    }

    const float* bias = (z == 0) ? bk : (z == 1) ? bq : bv;
    ushort* dstA = (z == 0) ? kd : qd;
    for (int fr = 0; fr < 4; fr++) {
        int ibase = row0 + wr * 64 + fr * 16 + quad * 4;
        int b_ = ibase >> 10, s = ibase & 1023;
        for (int fc = 0; fc < 4; fc++) {
            int j = col0 + wc * 64 + fc * 16 + m15;
            int h = j >> 6, dh = j & 63;
            float bb = bias[j];
            if (z < 2) {
                for (int r = 0; r < 4; r++)
                    dstA[((b_ * 16 + h) * 1024 + (s + r)) * 64 + dh] = f2bf(acc[fr][fc][r] + bb);
            } else {
                ushort4 o;
                o.x = f2bf(acc[fr][fc][0] + bb);
                o.y = f2bf(acc[fr][fc][1] + bb);
                o.z = f2bf(acc[fr][fc][2] + bb);
                o.w = f2bf(acc[fr][fc][3] + bb);
                *(ushort4*)&vd[((b_ * 16 + h) * 64 + dh) * 1024 + s] = o;
            }
        }
    }
}

// ---------------- lm[m,s,u] = sum_r mask1[m,r,s]*mask2[m,r,u] ----------------
__global__ __launch_bounds__(256) void mask_lr(const float* __restrict__ m1,
                                               const float* __restrict__ m2,
                                               float* __restrict__ lm)
{
    __shared__ float As[64 * 64];
    __shared__ float Bs2[64 * 64];
    const int m = blockIdx.z;
    const int s0 = blockIdx.x * 64, u0 = blockIdx.y * 64;
    const int tid = threadIdx.x;
    for (int i = 0; i < 4; i++) {
        int c = tid + i * 256;              // 1024 float4 chunks
        int r = c >> 4, off = (c & 15) * 4;
        *(float4*)&As[r * 64 + off]  = *(const float4*)&m1[(m * 64 + r) * 1024 + s0 + off];
        *(float4*)&Bs2[r * 64 + off] = *(const float4*)&m2[(m * 64 + r) * 1024 + u0 + off];
    }
    __syncthreads();
    const int tx = tid & 15, ty = tid >> 4;
    float acc[4][4] = {};
    for (int r = 0; r < 64; r++) {
        float4 a = *(const float4*)&As[r * 64 + ty * 4];
        float4 b = *(const float4*)&Bs2[r * 64 + tx * 4];
        float aa[4] = {a.x, a.y, a.z, a.w}, bb[4] = {b.x, b.y, b.z, b.w};
        for (int i = 0; i < 4; i++)
            for (int j = 0; j < 4; j++) acc[i][j] += aa[i] * bb[j];
    }
    for (int i = 0; i < 4; i++) {
        float4 o = {acc[i][0], acc[i][1], acc[i][2], acc[i][3]};
        *(float4*)&lm[(m * 1024 + s0 + ty * 4 + i) * 1024 + u0 + tx * 4] = o;
    }
}

// ---------------- gathered[m,s,t] = lm[m,s,rb[m,s,t]] * 0.125 ----------------
__global__ __launch_bounds__(256) void mask_gather(const float* __restrict__ lm,
                                                   const int* __restrict__ rb,
                                                   float* __restrict__ gth)
{
    __shared__ float row[1024];
    const int s = blockIdx.x, m = blockIdx.y;
    const int tid = threadIdx.x;
    const int base = (m * 1024 + s) * 1024;
    *(float4*)&row[tid * 4] = *(const float4*)&lm[base + tid * 4];
    __syncthreads();
    int4 idx = ((const int4*)(rb + base))[tid];
    float4 o;
    o.x = row[idx.x & 1023] * 0.125f;
    o.y = row[idx.y & 1023] * 0.125f;
    o.z = row[idx.z & 1023] * 0.125f;
    o.w = row[idx.w & 1023] * 0.125f;
    ((float4*)(gth + base))[tid] = o;
}

// ---------------- fused attention: O_unnorm = (QK^T*mask) @ V ; ss = sum P^2 ----------------
// q,k: [B,H,S,64] bf16 ; v: [B,H,64,S] bf16 ; gth: [4,S,S] f32 (scale folded in)
__global__ __launch_bounds__(256) void attention(
    const ushort* __restrict__ qd, const ushort* __restrict__ kd, const ushort* __restrict__ vd,
    const float* __restrict__ gth, float* __restrict__ O, float* __restrict__ ss)
{
    __shared__ ushort Qs[64 * 72];
    __shared__ ushort Ks[64 * 72];
    __shared__ ushort Vs[64 * 72];
    __shared__ ushort Ps[64 * 72];
    __shared__ float red[4];
    const int s0 = blockIdx.x * 64;
    const int bh = blockIdx.y;
    const int h = bh & 15, mm = h & 3;
    const int tid = threadIdx.x, lane = tid & 63, wave = tid >> 6;
    const int quad = lane >> 4, m15 = lane & 15;
    const int wr = wave >> 1, wc = wave & 1;

    for (int i = 0; i < 2; i++) {          // stage Q tile [64 s][64 dh]
        int c = tid + i * 256;
        int r = c >> 3, off = (c & 7) * 8;
        *(uint4*)&Qs[r * 72 + off] = *(const uint4*)&qd[(bh * 1024 + s0 + r) * 64 + off];
    }
    f32x4 oacc[4];
    for (int i = 0; i < 4; i++) oacc[i] = (f32x4){0.f, 0.f, 0.f, 0.f};
    float ssacc = 0.f;
    const float* gbase = gth + mm * 1048576 + s0 * 1024;

    for (int t0 = 0; t0 < 1024; t0 += 64) {
        __syncthreads();                   // prev-iter readers done before restage
        for (int i = 0; i < 2; i++) {
            int c = tid + i * 256;
            int r = c >> 3, off = (c & 7) * 8;
            *(uint4*)&Ks[r * 72 + off] = *(const uint4*)&kd[(bh * 1024 + t0 + r) * 64 + off];
            *(uint4*)&Vs[r * 72 + off] = *(const uint4*)&vd[(bh * 64 + r) * 1024 + t0 + off];
        }
        __syncthreads();
        // QK^T on wave region rows [wr*32,+32) cols [wc*32,+32), then mask+store P
        for (int fr = 0; fr < 2; fr++) {
            int srow = wr * 32 + fr * 16;
            for (int fc = 0; fc < 2; fc++) {
                int tcol = wc * 32 + fc * 16;
                f32x4 p = (f32x4){0.f, 0.f, 0.f, 0.f};
                for (int kk = 0; kk < 64; kk += 32) {
                    bf16x8 a = *(const bf16x8*)&Qs[(srow + m15) * 72 + kk + quad * 8];
                    bf16x8 b = *(const bf16x8*)&Ks[(tcol + m15) * 72 + kk + quad * 8];
                    p = __builtin_amdgcn_mfma_f32_16x16x32_bf16(a, b, p, 0, 0, 0);
                }
                const float* gp = gbase + (srow + quad * 4) * 1024 + t0 + tcol + m15;
                ushort* pp = &Ps[(srow + quad * 4) * 72 + tcol + m15];
                for (int r = 0; r < 4; r++) {
                    float pv = p[r] * gp[r * 1024];
                    ssacc += pv * pv;
                    pp[r * 72] = f2bf(pv);
                }
            }
        }
        __syncthreads();
        // PV: wave computes O rows [wave*16,+16), all 64 dh cols
        for (int kk = 0; kk < 64; kk += 32) {
            bf16x8 a = *(const bf16x8*)&Ps[(wave * 16 + m15) * 72 + kk + quad * 8];
            for (int fc = 0; fc < 4; fc++) {
                bf16x8 b = *(const bf16x8*)&Vs[(fc * 16 + m15) * 72 + kk + quad * 8];
                oacc[fc] = __builtin_amdgcn_mfma_f32_16x16x32_bf16(a, b, oacc[fc], 0, 0, 0);
            }
        }
    }
    for (int fc = 0; fc < 4; fc++)
        for (int r = 0; r < 4; r++) {
            int s = s0 + wave * 16 + quad * 4 + r;
            O[(bh * 1024 + s) * 64 + fc * 16 + m15] = oacc[fc][r];
        }
    for (int off = 32; off; off >>= 1) ssacc += __shfl_down(ssacc, off, 64);
    if (lane == 0) red[wave] = ssacc;
    __syncthreads();
    if (tid == 0) atomicAdd(&ss[bh], red[0] + red[1] + red[2] + red[3]);
}

// ---------------- normalize + transpose to [B,S,H,DH] ----------------
__global__ __launch_bounds__(256) void normalize_out(const float* __restrict__ O,
                                                     const float* __restrict__ ss,
                                                     float* __restrict__ out)
{
    int gid = blockIdx.x * 256 + threadIdx.x;
    int e = gid * 4;
    int bh = e >> 16;
    float inv = 1.f / (sqrtf(ss[bh]) + 1e-8f);
    float4 v4 = *(const float4*)&O[e];
    int b_ = bh >> 4, h = bh & 15;
    int s = (e >> 6) & 1023, dh = e & 63;
    float4 o4 = {v4.x * inv, v4.y * inv, v4.z * inv, v4.w * inv};
    *(float4*)&out[((b_ * 1024 + s) * 16 + h) * 64 + dh] = o4;
}

extern "C" void kernel_launch(void* const* d_in, const int* in_sizes, int n_in,
                              void* d_out, int out_size, void* d_ws, size_t ws_size,
                              hipStream_t stream) {
    const float* x  = (const float*)d_in[0];
    const float* Wk = (const float*)d_in[1];
    const float* bk = (const float*)d_in[2];
    const float* Wq = (const float*)d_in[3];
    const float* bq = (const float*)d_in[4];
    const float* Wv = (const float*)d_in[5];
    const float* bv = (const float*)d_in[6];
    const float* m1 = (const float*)d_in[7];
    const float* m2 = (const float*)d_in[8];
    const int*   rb = (const int*)d_in[9];
    float* out = (float*)d_out;

    char* ws = (char*)d_ws;
    ushort* xb    = (ushort*)(ws);                  //  8 MB  [4096,1024] bf16
    ushort* wball = (ushort*)(ws + 8388608);        //  6 MB  3x[1024,1024] bf16
    ushort* kd    = (ushort*)(ws + 14680064);       //  8 MB  [B,H,S,DH] bf16
    ushort* qd    = (ushort*)(ws + 23068672);       //  8 MB
    ushort* vd    = (ushort*)(ws + 31457280);       //  8 MB  [B,H,DH,S] bf16
    float*  lm    = (float*)(ws + 39845888);        // 16 MB  [M,S,S] f32 (reused as O)
    float*  gth   = (float*)(ws + 56623104);        // 16 MB  [M,S,S] f32
    float*  ssb   = (float*)(ws + 73400320);        // 64 f32

    convert_bf16<<<4096, 256, 0, stream>>>(x,  xb, 1048576);
    convert_bf16<<<1024, 256, 0, stream>>>(Wk, wball,           262144);
    convert_bf16<<<1024, 256, 0, stream>>>(Wq, wball + 1048576, 262144);
    convert_bf16<<<1024, 256, 0, stream>>>(Wv, wball + 2097152, 262144);
    proj_gemm<<<dim3(32, 8, 3), 256, 0, stream>>>(xb, wball, bk, bq, bv, kd, qd, vd);
    mask_lr<<<dim3(16, 16, 4), 256, 0, stream>>>(m1, m2, lm);
    mask_gather<<<dim3(1024, 4), 256, 0, stream>>>(lm, rb, gth);
    hipMemsetAsync(ssb, 0, 64 * sizeof(float), stream);
    float* O = lm;   // lm dead after mask_gather
    attention<<<dim3(16, 64), 256, 0, stream>>>(qd, kd, vd, gth, O, ssb);
    normalize_out<<<4096, 256, 0, stream>>>(O, ssb, out);
}